// Round 1
// baseline (1095.321 us; speedup 1.0000x reference)
//
#include <hip/hip_runtime.h>
#include <hip/hip_bf16.h>

// GRU-D style decay LSTM: B=4096, T=48, IN=128, H=512.
// Key facts: batch rows independent (no grid sync); M binary => W_hr path dead;
// bf16 MFMA ok (threshold 2e-2, contracting recurrence).

#define B_TOT 4096
#define T_LEN 48
#define INDIM 128
#define HDIM  512

#define BROWS    32                 // batch rows per block
#define NWAVES   8                  // 8 waves, each owns 64 output cols
#define NTHREADS (NWAVES * 64)      // 512
#define NBLOCKS  (B_TOT / BROWS)    // 128

#define HB_STRIDE 520               // 512 + 8 pad (bf16 elems) -> 2-way-bank only
#define XB_STRIDE 136               // 128 + 8 pad

typedef __attribute__((ext_vector_type(8))) short bf16x8;
typedef __attribute__((ext_vector_type(4))) float f32x4;

__device__ __forceinline__ short f2bf(float f) {           // RTNE f32->bf16
  unsigned u = __float_as_uint(f);
  u += 0x7fff + ((u >> 16) & 1);
  return (short)(u >> 16);
}
__device__ __forceinline__ float bf2f(short s) {
  return __uint_as_float(((unsigned)(unsigned short)s) << 16);
}

// Pack fp32 weights into bf16 MFMA B-fragment order for 16x16x32:
// B[k][n] = trans ? src[n*ld+k] : src[k*ld+n]
// dst[((nt*KT + kt)*64 + lane)*8 + j] = B[kt*32 + (lane>>4)*8 + j][nt*16 + (lane&15)]
__global__ void pack_b_kernel(const float* __restrict__ src, short* __restrict__ dst,
                              int KT, int ld, int trans) {
  int gid  = blockIdx.x * blockDim.x + threadIdx.x;   // one fragment-lane each
  int lane = gid & 63;
  int kt   = (gid >> 6) % KT;
  int nt   = (gid >> 6) / KT;
  int n     = nt * 16 + (lane & 15);
  int kbase = kt * 32 + ((lane >> 4) << 3);
  bf16x8 v;
#pragma unroll
  for (int j = 0; j < 8; ++j) {
    int k = kbase + j;
    float f = trans ? src[(size_t)n * ld + k] : src[(size_t)k * ld + n];
    v[j] = f2bf(f);
  }
  *(bf16x8*)&dst[(size_t)gid * 8] = v;
}

__global__ __launch_bounds__(NTHREADS) void lstm_main(
    const float* __restrict__ X, const float* __restrict__ M,
    const float* __restrict__ b_td, const float* __restrict__ b_h,
    const short* __restrict__ Wtd_b, const short* __restrict__ Wh_b,
    const short* __restrict__ Uh_b, float* __restrict__ out) {
  __shared__ short hbuf[BROWS * HB_STRIDE];   // h (then h*gamma) bf16
  __shared__ short mxbuf[BROWS * XB_STRIDE];  // m*x bf16
  __shared__ short mbuf[BROWS * XB_STRIDE];   // m bf16 (for next-step d update)
  __shared__ short dbuf[BROWS * XB_STRIDE];   // decay counters (exact ints in bf16)

  const int tid  = threadIdx.x;
  const int lane = tid & 63;
  const int wave = tid >> 6;           // 0..7 -> output col slice wave*64
  const int l15  = lane & 15;
  const int lk   = (lane >> 4) << 3;   // k offset within fragment: 0,8,16,24
  const int browbase = blockIdx.x * BROWS;

  for (int i = tid; i < BROWS * HB_STRIDE; i += NTHREADS) hbuf[i] = 0;  // h0 = 0
  for (int i = tid; i < BROWS * XB_STRIDE; i += NTHREADS) dbuf[i] = 0;  // D[0] = 0

  float btd_r[4], bh_r[4];
#pragma unroll
  for (int nt = 0; nt < 4; ++nt) {
    int col = wave * 64 + nt * 16 + l15;
    btd_r[nt] = b_td[col];
    bh_r[nt]  = b_h[col];
  }

  // X/M staging: 512 threads x 8 floats = 32 rows x 128
  const int lrow = tid >> 4;
  const int lcol = (tid & 15) << 3;
  const float* xbase = X + (size_t)(browbase + lrow) * T_LEN * INDIM + lcol;
  const float* mbase = M + (size_t)(browbase + lrow) * T_LEN * INDIM + lcol;

  __syncthreads();

  for (int t = 0; t < T_LEN; ++t) {
    // ---- Phase A: d = 1 + (m_prev==0)*d  (same thread owns same elems as B) ----
    if (t > 0) {
      bf16x8 mp = *(const bf16x8*)&mbuf[lrow * XB_STRIDE + lcol];
      bf16x8 dp = *(const bf16x8*)&dbuf[lrow * XB_STRIDE + lcol];
      bf16x8 dn;
#pragma unroll
      for (int j = 0; j < 8; ++j) {
        float m = bf2f(mp[j]);
        float d = bf2f(dp[j]);
        dn[j] = f2bf(1.f + (m == 0.f ? d : 0.f));
      }
      *(bf16x8*)&dbuf[lrow * XB_STRIDE + lcol] = dn;
    }
    // ---- Phase B: stage m*x and m ----
    {
      const float* xp = xbase + (size_t)t * INDIM;
      const float* mp = mbase + (size_t)t * INDIM;
      float4 xa = *(const float4*)xp;
      float4 xb = *(const float4*)(xp + 4);
      float4 ma = *(const float4*)mp;
      float4 mb = *(const float4*)(mp + 4);
      bf16x8 mxv, mv;
      mxv[0] = f2bf(ma.x * xa.x); mv[0] = f2bf(ma.x);
      mxv[1] = f2bf(ma.y * xa.y); mv[1] = f2bf(ma.y);
      mxv[2] = f2bf(ma.z * xa.z); mv[2] = f2bf(ma.z);
      mxv[3] = f2bf(ma.w * xa.w); mv[3] = f2bf(ma.w);
      mxv[4] = f2bf(mb.x * xb.x); mv[4] = f2bf(mb.x);
      mxv[5] = f2bf(mb.y * xb.y); mv[5] = f2bf(mb.y);
      mxv[6] = f2bf(mb.z * xb.z); mv[6] = f2bf(mb.z);
      mxv[7] = f2bf(mb.w * xb.w); mv[7] = f2bf(mb.w);
      *(bf16x8*)&mxbuf[lrow * XB_STRIDE + lcol] = mxv;
      *(bf16x8*)&mbuf[lrow * XB_STRIDE + lcol]  = mv;
    }
    __syncthreads();

    // ---- Phase C: gamma = exp(-relu(d @ Wtd^T + b_td)); hbuf *= gamma (in place) ----
    f32x4 gacc[2][4];
#pragma unroll
    for (int mt = 0; mt < 2; ++mt)
#pragma unroll
      for (int nt = 0; nt < 4; ++nt) gacc[mt][nt] = (f32x4){0.f, 0.f, 0.f, 0.f};
#pragma unroll
    for (int kt = 0; kt < 4; ++kt) {
      bf16x8 a0 = *(const bf16x8*)&dbuf[l15 * XB_STRIDE + kt * 32 + lk];
      bf16x8 a1 = *(const bf16x8*)&dbuf[(16 + l15) * XB_STRIDE + kt * 32 + lk];
#pragma unroll
      for (int nt = 0; nt < 4; ++nt) {
        bf16x8 b = *(const bf16x8*)&Wtd_b[(size_t)(((wave * 4 + nt) * 4 + kt) * 64 + lane) * 8];
        gacc[0][nt] = __builtin_amdgcn_mfma_f32_16x16x32_bf16(a0, b, gacc[0][nt], 0, 0, 0);
        gacc[1][nt] = __builtin_amdgcn_mfma_f32_16x16x32_bf16(a1, b, gacc[1][nt], 0, 0, 0);
      }
    }
#pragma unroll
    for (int mt = 0; mt < 2; ++mt)
#pragma unroll
      for (int nt = 0; nt < 4; ++nt)
#pragma unroll
        for (int i = 0; i < 4; ++i) {
          int row = mt * 16 + ((lane >> 4) << 2) + i;   // C/D: row = 4*(lane>>4)+reg
          int col = wave * 64 + nt * 16 + l15;          //      col = lane&15
          float gam = __expf(-fmaxf(gacc[mt][nt][i] + btd_r[nt], 0.f));
          int idx = row * HB_STRIDE + col;
          hbuf[idx] = f2bf(bf2f(hbuf[idx]) * gam);
        }
    __syncthreads();

    // ---- Phase D: pre = hg @ W_h + (m*x) @ U_h ----
    f32x4 acc[2][4];
#pragma unroll
    for (int mt = 0; mt < 2; ++mt)
#pragma unroll
      for (int nt = 0; nt < 4; ++nt) acc[mt][nt] = (f32x4){0.f, 0.f, 0.f, 0.f};
#pragma unroll 4
    for (int kt = 0; kt < 16; ++kt) {
      bf16x8 a0 = *(const bf16x8*)&hbuf[l15 * HB_STRIDE + kt * 32 + lk];
      bf16x8 a1 = *(const bf16x8*)&hbuf[(16 + l15) * HB_STRIDE + kt * 32 + lk];
#pragma unroll
      for (int nt = 0; nt < 4; ++nt) {
        bf16x8 b = *(const bf16x8*)&Wh_b[(size_t)(((wave * 4 + nt) * 16 + kt) * 64 + lane) * 8];
        acc[0][nt] = __builtin_amdgcn_mfma_f32_16x16x32_bf16(a0, b, acc[0][nt], 0, 0, 0);
        acc[1][nt] = __builtin_amdgcn_mfma_f32_16x16x32_bf16(a1, b, acc[1][nt], 0, 0, 0);
      }
    }
#pragma unroll
    for (int kt = 0; kt < 4; ++kt) {
      bf16x8 a0 = *(const bf16x8*)&mxbuf[l15 * XB_STRIDE + kt * 32 + lk];
      bf16x8 a1 = *(const bf16x8*)&mxbuf[(16 + l15) * XB_STRIDE + kt * 32 + lk];
#pragma unroll
      for (int nt = 0; nt < 4; ++nt) {
        bf16x8 b = *(const bf16x8*)&Uh_b[(size_t)(((wave * 4 + nt) * 4 + kt) * 64 + lane) * 8];
        acc[0][nt] = __builtin_amdgcn_mfma_f32_16x16x32_bf16(a0, b, acc[0][nt], 0, 0, 0);
        acc[1][nt] = __builtin_amdgcn_mfma_f32_16x16x32_bf16(a1, b, acc[1][nt], 0, 0, 0);
      }
    }
    __syncthreads();   // everyone done reading hg before overwrite

    // ---- Phase E: h = sigmoid(pre + b_h); write LDS bf16 + global fp32 ----
#pragma unroll
    for (int mt = 0; mt < 2; ++mt)
#pragma unroll
      for (int nt = 0; nt < 4; ++nt)
#pragma unroll
        for (int i = 0; i < 4; ++i) {
          int row = mt * 16 + ((lane >> 4) << 2) + i;
          int col = wave * 64 + nt * 16 + l15;
          float pre = acc[mt][nt][i] + bh_r[nt];
          float h = 1.f / (1.f + __expf(-pre));
          hbuf[row * HB_STRIDE + col] = f2bf(h);
          out[((size_t)(browbase + row) * T_LEN + t) * HDIM + col] = h;
        }
    __syncthreads();
  }
}

extern "C" void kernel_launch(void* const* d_in, const int* in_sizes, int n_in,
                              void* d_out, int out_size, void* d_ws, size_t ws_size,
                              hipStream_t stream) {
  const float* X    = (const float*)d_in[0];
  const float* M    = (const float*)d_in[1];
  const float* W_td = (const float*)d_in[2];
  const float* b_td = (const float*)d_in[3];
  // d_in[4] = W_hr, d_in[5] = b_hr : dead code because M is binary
  const float* W_h  = (const float*)d_in[6];
  const float* U_h  = (const float*)d_in[7];
  const float* b_h  = (const float*)d_in[8];
  float* out = (float*)d_out;

  short* ws    = (short*)d_ws;
  short* Wtd_b = ws;                      // 512x128 -> 65536 bf16
  short* Wh_b  = ws + 65536;              // 512x512 -> 262144 bf16
  short* Uh_b  = ws + 65536 + 262144;     // 128x512 -> 65536 bf16

  // gamma path: B[k=i][n] = W_td[n][i]  (trans, ld=128, KT=4)
  pack_b_kernel<<<32, 256, 0, stream>>>(W_td, Wtd_b, 4, 128, 1);
  // main path:  B[k][n] = W_h[k][n]     (ld=512, KT=16)
  pack_b_kernel<<<128, 256, 0, stream>>>(W_h, Wh_b, 16, 512, 0);
  //             B[k][n] = U_h[k][n]     (ld=512, KT=4)
  pack_b_kernel<<<32, 256, 0, stream>>>(U_h, Uh_b, 4, 512, 0);

  lstm_main<<<NBLOCKS, NTHREADS, 0, stream>>>(X, M, b_td, b_h, Wtd_b, Wh_b, Uh_b, out);
}